// Round 1
// baseline (113.340 us; speedup 1.0000x reference)
//
#include <hip/hip_runtime.h>
#include <math.h>

#define H 1024
#define V 50257
#define S 8192

__device__ __forceinline__ float wave_reduce_sum(float v) {
    #pragma unroll
    for (int o = 32; o > 0; o >>= 1) v += __shfl_down(v, o, 64);
    return v;
}

// K1: gi = W_ih @ x + b_ih ; gh = W_hh @ h + b_hh   (one wave per row, 6144 rows)
__global__ __launch_bounds__(256) void k_gates(
    const float* __restrict__ Wih, const float* __restrict__ Whh,
    const float* __restrict__ bih, const float* __restrict__ bhh,
    const float* __restrict__ emb, const int* __restrict__ word,
    const float* __restrict__ h0, float* __restrict__ gi, float* __restrict__ gh) {
  int wave = threadIdx.x >> 6, lane = threadIdx.x & 63;
  int row = blockIdx.x * 4 + wave;          // 0..6143
  const float* W; const float* x; const float* b; float* out; int r;
  if (row < 3 * H) { W = Wih; x = emb + (size_t)word[0] * H; b = bih; out = gi; r = row; }
  else             { W = Whh; x = h0;                        b = bhh; out = gh; r = row - 3 * H; }
  const float4* Wr = (const float4*)(W + (size_t)r * H);
  const float4* xv = (const float4*)x;
  float acc = 0.f;
  #pragma unroll
  for (int u = 0; u < 4; ++u) {
    float4 w = Wr[lane + u * 64];
    float4 xx = xv[lane + u * 64];
    acc += w.x * xx.x + w.y * xx.y + w.z * xx.z + w.w * xx.w;
  }
  acc = wave_reduce_sum(acc);
  if (lane == 0) out[r] = acc + b[r];
}

// K2: GRU combine -> h_new (into xv[0:H] and d_out), c0 = dot(b_attn, h_new)
__global__ __launch_bounds__(1024) void k_gru(
    const float* __restrict__ gi, const float* __restrict__ gh,
    const float* __restrict__ h0, const float* __restrict__ battn,
    float* __restrict__ xv, float* __restrict__ c0, float* __restrict__ out_h) {
  __shared__ float red[16];
  int i = threadIdx.x;
  float r = 1.f / (1.f + __expf(-(gi[i] + gh[i])));
  float z = 1.f / (1.f + __expf(-(gi[H + i] + gh[H + i])));
  float n = tanhf(gi[2 * H + i] + r * gh[2 * H + i]);
  float hn = (1.f - z) * n + z * h0[i];
  xv[i] = hn;
  out_h[i] = hn;
  float p = battn[i] * hn;
  float w = wave_reduce_sum(p);
  if ((i & 63) == 0) red[i >> 6] = w;
  __syncthreads();
  if (i == 0) {
    float s = 0.f;
    #pragma unroll
    for (int k = 0; k < 16; ++k) s += red[k];
    c0[0] = s;
  }
}

// K3: vpart[c][k] = sum_{j in chunk c} W_attn[j][k] * h_new[j]   (32 chunks of 32 rows)
__global__ __launch_bounds__(1024) void k_vpart(
    const float* __restrict__ Wattn, const float* __restrict__ xv,
    float* __restrict__ vpart) {
  int k = threadIdx.x;
  int j0 = blockIdx.x * 32;
  float acc = 0.f;
  #pragma unroll 8
  for (int j = 0; j < 32; ++j)
    acc += Wattn[(size_t)(j0 + j) * H + k] * xv[j0 + j];
  vpart[blockIdx.x * H + k] = acc;
}

__global__ __launch_bounds__(1024) void k_vred(const float* __restrict__ vpart,
                                               float* __restrict__ v) {
  int k = threadIdx.x;
  float a = 0.f;
  #pragma unroll
  for (int c = 0; c < 32; ++c) a += vpart[c * H + k];
  v[k] = a;
}

// K4: scores[s] = dot(enc[s], v) + c0   (one wave per s)
__global__ __launch_bounds__(256) void k_scores(
    const float* __restrict__ enc, const float* __restrict__ v,
    const float* __restrict__ c0, float* __restrict__ scores) {
  int wave = threadIdx.x >> 6, lane = threadIdx.x & 63;
  int s = blockIdx.x * 4 + wave;
  const float4* er = (const float4*)(enc + (size_t)s * H);
  const float4* vv = (const float4*)v;
  float acc = 0.f;
  #pragma unroll
  for (int u = 0; u < 4; ++u) {
    float4 e = er[lane + u * 64];
    float4 w = vv[lane + u * 64];
    acc += e.x * w.x + e.y * w.y + e.z * w.z + e.w * w.w;
  }
  acc = wave_reduce_sum(acc);
  if (lane == 0) scores[s] = acc + c0[0];
}

// K5: softmax over scores[8192]; write attn to ws (reuse scores) and d_out
__global__ __launch_bounds__(1024) void k_softmax(float* __restrict__ scores,
                                                  float* __restrict__ attn_out) {
  __shared__ float red[16];
  __shared__ float bc[2];
  int t = threadIdx.x;
  float vals[8];
  float m = -1e30f;
  #pragma unroll
  for (int u = 0; u < 8; ++u) { vals[u] = scores[u * 1024 + t]; m = fmaxf(m, vals[u]); }
  #pragma unroll
  for (int o = 32; o > 0; o >>= 1) m = fmaxf(m, __shfl_down(m, o, 64));
  if ((t & 63) == 0) red[t >> 6] = m;
  __syncthreads();
  if (t == 0) {
    float mm = red[0];
    #pragma unroll
    for (int k = 1; k < 16; ++k) mm = fmaxf(mm, red[k]);
    bc[0] = mm;
  }
  __syncthreads();
  m = bc[0];
  float s = 0.f;
  #pragma unroll
  for (int u = 0; u < 8; ++u) { vals[u] = __expf(vals[u] - m); s += vals[u]; }
  s = wave_reduce_sum(s);
  if ((t & 63) == 0) red[t >> 6] = s;
  __syncthreads();
  if (t == 0) {
    float ss = 0.f;
    #pragma unroll
    for (int k = 0; k < 16; ++k) ss += red[k];
    bc[1] = 1.f / ss;
  }
  __syncthreads();
  float inv = bc[1];
  #pragma unroll
  for (int u = 0; u < 8; ++u) {
    float a = vals[u] * inv;
    scores[u * 1024 + t] = a;
    attn_out[u * 1024 + t] = a;
  }
}

// K6: cpart[c][k] = sum_{s in chunk c} attn[s] * enc[s][k]   (64 chunks of 128 rows)
__global__ __launch_bounds__(1024) void k_cpart(
    const float* __restrict__ enc, const float* __restrict__ attn,
    float* __restrict__ cpart) {
  int k = threadIdx.x;
  int s0 = blockIdx.x * 128;
  float acc = 0.f;
  #pragma unroll 8
  for (int j = 0; j < 128; ++j)
    acc += attn[s0 + j] * enc[(size_t)(s0 + j) * H + k];
  cpart[blockIdx.x * H + k] = acc;
}

__global__ __launch_bounds__(1024) void k_cred(const float* __restrict__ cpart,
                                               float* __restrict__ ctx) {
  int k = threadIdx.x;
  float a = 0.f;
  #pragma unroll
  for (int c = 0; c < 64; ++c) a += cpart[c * H + k];
  ctx[k] = a;
}

// K7: logits = W_out @ [h_new; context] + b_out   (one wave per row, 412 MB read)
__global__ __launch_bounds__(256) void k_logits(
    const float* __restrict__ Wout, const float* __restrict__ xv,
    const float* __restrict__ bout, float* __restrict__ logits) {
  __shared__ float4 sx[512];          // the 2048-float input vector
  int t = threadIdx.x;
  const float4* xv4 = (const float4*)xv;
  sx[t] = xv4[t];
  sx[t + 256] = xv4[t + 256];
  __syncthreads();
  int wave = t >> 6, lane = t & 63;
  int row = blockIdx.x * 4 + wave;
  if (row < V) {
    const float4* wr = (const float4*)(Wout + (size_t)row * 2 * H);
    float acc = 0.f;
    #pragma unroll
    for (int u = 0; u < 8; ++u) {
      float4 w = wr[lane + u * 64];
      float4 x = sx[lane + u * 64];
      acc += w.x * x.x + w.y * x.y + w.z * x.z + w.w * x.w;
    }
    acc = wave_reduce_sum(acc);
    if (lane == 0) logits[row] = acc + bout[row];
  }
}

extern "C" void kernel_launch(void* const* d_in, const int* in_sizes, int n_in,
                              void* d_out, int out_size, void* d_ws, size_t ws_size,
                              hipStream_t stream) {
  const int*   word  = (const int*)d_in[0];
  const float* h0    = (const float*)d_in[1];
  const float* enc   = (const float*)d_in[2];
  const float* emb   = (const float*)d_in[3];
  const float* Wattn = (const float*)d_in[4];
  const float* battn = (const float*)d_in[5];
  const float* Wih   = (const float*)d_in[6];
  const float* bih   = (const float*)d_in[7];
  const float* Whh   = (const float*)d_in[8];
  const float* bhh   = (const float*)d_in[9];
  const float* Wout  = (const float*)d_in[10];
  const float* bout  = (const float*)d_in[11];
  float* out = (float*)d_out;
  float* ws  = (float*)d_ws;

  float* gi     = ws;            // 3072
  float* gh     = ws + 3072;     // 3072
  float* xv     = ws + 6144;     // 2048 = [h_new ; context]
  float* v      = ws + 8192;     // 1024
  float* c0     = ws + 9216;     // 16
  float* scores = ws + 9232;     // 8192 (reused as attn)
  float* vpart  = ws + 17424;    // 32*1024
  float* cpart  = ws + 50192;    // 64*1024  (end: 115728 floats ≈ 463 KB)

  k_gates  <<<1536, 256, 0, stream>>>(Wih, Whh, bih, bhh, emb, word, h0, gi, gh);
  k_gru    <<<1, 1024, 0, stream>>>(gi, gh, h0, battn, xv, c0, out + V);
  k_vpart  <<<32, 1024, 0, stream>>>(Wattn, xv, vpart);
  k_vred   <<<1, 1024, 0, stream>>>(vpart, v);
  k_scores <<<2048, 256, 0, stream>>>(enc, v, c0, scores);
  k_softmax<<<1, 1024, 0, stream>>>(scores, out + V + H);
  k_cpart  <<<64, 1024, 0, stream>>>(enc, scores, cpart);
  k_cred   <<<1, 1024, 0, stream>>>(cpart, xv + H);
  k_logits <<<(V + 3) / 4, 256, 0, stream>>>(Wout, xv, bout, out);
}

// Round 2
// 106.000 us; speedup vs baseline: 1.0692x; 1.0692x over previous
//
#include <hip/hip_runtime.h>
#include <math.h>

#define H 1024
#define V 50257
#define S 8192

__device__ __forceinline__ float wave_reduce_sum(float v) {
    #pragma unroll
    for (int o = 32; o > 0; o >>= 1) v += __shfl_down(v, o, 64);
    return v;
}

// K1: gi = W_ih @ x + b_ih ; gh = W_hh @ h + b_hh   (one wave per row, 6144 rows)
__global__ __launch_bounds__(256) void k_gates(
    const float* __restrict__ Wih, const float* __restrict__ Whh,
    const float* __restrict__ bih, const float* __restrict__ bhh,
    const float* __restrict__ emb, const int* __restrict__ word,
    const float* __restrict__ h0, float* __restrict__ gi, float* __restrict__ gh) {
  int wave = threadIdx.x >> 6, lane = threadIdx.x & 63;
  int row = blockIdx.x * 4 + wave;          // 0..6143
  const float* W; const float* x; const float* b; float* out; int r;
  if (row < 3 * H) { W = Wih; x = emb + (size_t)word[0] * H; b = bih; out = gi; r = row; }
  else             { W = Whh; x = h0;                        b = bhh; out = gh; r = row - 3 * H; }
  const float4* Wr = (const float4*)(W + (size_t)r * H);
  const float4* xv = (const float4*)x;
  float acc = 0.f;
  #pragma unroll
  for (int u = 0; u < 4; ++u) {
    float4 w = Wr[lane + u * 64];
    float4 xx = xv[lane + u * 64];
    acc += w.x * xx.x + w.y * xx.y + w.z * xx.z + w.w * xx.w;
  }
  acc = wave_reduce_sum(acc);
  if (lane == 0) out[r] = acc + b[r];
}

// K2: GRU combine -> h_new (xv[0:H] and d_out), c0 = dot(b_attn,h_new); zero v, ctx
__global__ __launch_bounds__(1024) void k_gru(
    const float* __restrict__ gi, const float* __restrict__ gh,
    const float* __restrict__ h0, const float* __restrict__ battn,
    float* __restrict__ xv, float* __restrict__ v, float* __restrict__ c0,
    float* __restrict__ out_h) {
  __shared__ float red[16];
  int i = threadIdx.x;
  float r = 1.f / (1.f + __expf(-(gi[i] + gh[i])));
  float z = 1.f / (1.f + __expf(-(gi[H + i] + gh[H + i])));
  float n = tanhf(gi[2 * H + i] + r * gh[2 * H + i]);
  float hn = (1.f - z) * n + z * h0[i];
  xv[i] = hn;
  out_h[i] = hn;
  v[i] = 0.f;          // vpart atomics target
  xv[H + i] = 0.f;     // ctx atomics target
  float p = battn[i] * hn;
  float w = wave_reduce_sum(p);
  if ((i & 63) == 0) red[i >> 6] = w;
  __syncthreads();
  if (i == 0) {
    float s = 0.f;
    #pragma unroll
    for (int k = 0; k < 16; ++k) s += red[k];
    c0[0] = s;
  }
}

// K3: blocks 0..31: v += W_attn^T-chunk @ h_new (atomicAdd)
//     blocks 32.. : partial[row] = W_out[row, 0:H] @ h_new   (206 MB)
__global__ __launch_bounds__(256) void k_big1(
    const float* __restrict__ Wattn, const float* __restrict__ Wout,
    const float* __restrict__ xv, float* __restrict__ v,
    float* __restrict__ partial) {
  int t = threadIdx.x;
  if (blockIdx.x < 32) {
    __shared__ float sh[32];
    int j0 = blockIdx.x * 32;
    if (t < 32) sh[t] = xv[j0 + t];
    __syncthreads();
    const float4* Wa = (const float4*)Wattn;
    float4 acc = {0.f, 0.f, 0.f, 0.f};
    #pragma unroll 8
    for (int j = 0; j < 32; ++j) {
      float4 w = Wa[(size_t)(j0 + j) * 256 + t];
      float hj = sh[j];
      acc.x += hj * w.x; acc.y += hj * w.y; acc.z += hj * w.z; acc.w += hj * w.w;
    }
    atomicAdd(&v[4 * t + 0], acc.x);
    atomicAdd(&v[4 * t + 1], acc.y);
    atomicAdd(&v[4 * t + 2], acc.z);
    atomicAdd(&v[4 * t + 3], acc.w);
  } else {
    __shared__ float4 sx[256];
    sx[t] = ((const float4*)xv)[t];
    __syncthreads();
    int wave = t >> 6, lane = t & 63;
    int row = (blockIdx.x - 32) * 4 + wave;
    if (row < V) {
      const float4* wr = (const float4*)Wout + (size_t)row * 512;   // row stride 2048 f
      float acc = 0.f;
      #pragma unroll
      for (int u = 0; u < 4; ++u) {
        float4 w = wr[lane + u * 64];
        float4 x = sx[lane + u * 64];
        acc += w.x * x.x + w.y * x.y + w.z * x.z + w.w * x.w;
      }
      acc = wave_reduce_sum(acc);
      if (lane == 0) partial[row] = acc;
    }
  }
}

// K4: scores[s] = dot(enc[s], v) + c0   (one wave per s)
__global__ __launch_bounds__(256) void k_scores(
    const float* __restrict__ enc, const float* __restrict__ v,
    const float* __restrict__ c0, float* __restrict__ scores) {
  int wave = threadIdx.x >> 6, lane = threadIdx.x & 63;
  int s = blockIdx.x * 4 + wave;
  const float4* er = (const float4*)(enc + (size_t)s * H);
  const float4* vv = (const float4*)v;
  float acc = 0.f;
  #pragma unroll
  for (int u = 0; u < 4; ++u) {
    float4 e = er[lane + u * 64];
    float4 w = vv[lane + u * 64];
    acc += e.x * w.x + e.y * w.y + e.z * w.z + e.w * w.w;
  }
  acc = wave_reduce_sum(acc);
  if (lane == 0) scores[s] = acc + c0[0];
}

// K5: softmax over scores[8192]; attn -> scores (reuse) and d_out
__global__ __launch_bounds__(1024) void k_softmax(float* __restrict__ scores,
                                                  float* __restrict__ attn_out) {
  __shared__ float red[16];
  __shared__ float bc[2];
  int t = threadIdx.x;
  float vals[8];
  float m = -1e30f;
  #pragma unroll
  for (int u = 0; u < 8; ++u) { vals[u] = scores[u * 1024 + t]; m = fmaxf(m, vals[u]); }
  #pragma unroll
  for (int o = 32; o > 0; o >>= 1) m = fmaxf(m, __shfl_down(m, o, 64));
  if ((t & 63) == 0) red[t >> 6] = m;
  __syncthreads();
  if (t == 0) {
    float mm = red[0];
    #pragma unroll
    for (int k = 1; k < 16; ++k) mm = fmaxf(mm, red[k]);
    bc[0] = mm;
  }
  __syncthreads();
  m = bc[0];
  float s = 0.f;
  #pragma unroll
  for (int u = 0; u < 8; ++u) { vals[u] = __expf(vals[u] - m); s += vals[u]; }
  s = wave_reduce_sum(s);
  if ((t & 63) == 0) red[t >> 6] = s;
  __syncthreads();
  if (t == 0) {
    float ss = 0.f;
    #pragma unroll
    for (int k = 0; k < 16; ++k) ss += red[k];
    bc[1] = 1.f / ss;
  }
  __syncthreads();
  float inv = bc[1];
  #pragma unroll
  for (int u = 0; u < 8; ++u) {
    float a = vals[u] * inv;
    scores[u * 1024 + t] = a;
    attn_out[u * 1024 + t] = a;
  }
}

// K6: ctx[k] += sum_{s in chunk} attn[s]*enc[s][k]  (256 blocks x 32 rows, atomicAdd)
__global__ __launch_bounds__(1024) void k_ctx(
    const float* __restrict__ enc, const float* __restrict__ attn,
    float* __restrict__ ctx) {
  __shared__ float sa[32];
  int k = threadIdx.x;
  int s0 = blockIdx.x * 32;
  if (k < 32) sa[k] = attn[s0 + k];
  __syncthreads();
  float acc = 0.f;
  #pragma unroll 8
  for (int j = 0; j < 32; ++j)
    acc += sa[j] * enc[(size_t)(s0 + j) * H + k];
  atomicAdd(&ctx[k], acc);
}

// K7: out[row] = partial[row] + W_out[row, H:2H] @ ctx + b_out[row]
__global__ __launch_bounds__(256) void k_logits2(
    const float* __restrict__ Wout, const float* __restrict__ xv,
    const float* __restrict__ partial, const float* __restrict__ bout,
    float* __restrict__ logits) {
  __shared__ float4 sx[256];
  int t = threadIdx.x;
  sx[t] = ((const float4*)xv)[256 + t];   // ctx half
  __syncthreads();
  int wave = t >> 6, lane = t & 63;
  int row = blockIdx.x * 4 + wave;
  if (row < V) {
    const float4* wr = (const float4*)Wout + (size_t)row * 512 + 256;  // second half
    float acc = 0.f;
    #pragma unroll
    for (int u = 0; u < 4; ++u) {
      float4 w = wr[lane + u * 64];
      float4 x = sx[lane + u * 64];
      acc += w.x * x.x + w.y * x.y + w.z * x.z + w.w * x.w;
    }
    acc = wave_reduce_sum(acc);
    if (lane == 0) logits[row] = acc + partial[row] + bout[row];
  }
}

extern "C" void kernel_launch(void* const* d_in, const int* in_sizes, int n_in,
                              void* d_out, int out_size, void* d_ws, size_t ws_size,
                              hipStream_t stream) {
  const int*   word  = (const int*)d_in[0];
  const float* h0    = (const float*)d_in[1];
  const float* enc   = (const float*)d_in[2];
  const float* emb   = (const float*)d_in[3];
  const float* Wattn = (const float*)d_in[4];
  const float* battn = (const float*)d_in[5];
  const float* Wih   = (const float*)d_in[6];
  const float* bih   = (const float*)d_in[7];
  const float* Whh   = (const float*)d_in[8];
  const float* bhh   = (const float*)d_in[9];
  const float* Wout  = (const float*)d_in[10];
  const float* bout  = (const float*)d_in[11];
  float* out = (float*)d_out;
  float* ws  = (float*)d_ws;

  float* gi      = ws;            // 3072
  float* gh      = ws + 3072;     // 3072
  float* xv      = ws + 6144;     // 2048 = [h_new ; ctx]
  float* v       = ws + 8192;     // 1024
  float* c0      = ws + 9216;     // 16
  float* scores  = ws + 9232;     // 8192 (reused as attn)
  float* partial = ws + 17424;    // 50257 (logits h-half partials) -> end 67681 f (~271 KB)

  k_gates  <<<1536, 256, 0, stream>>>(Wih, Whh, bih, bhh, emb, word, h0, gi, gh);
  k_gru    <<<1, 1024, 0, stream>>>(gi, gh, h0, battn, xv, v, c0, out + V);
  k_big1   <<<32 + (V + 3) / 4, 256, 0, stream>>>(Wattn, Wout, xv, v, partial);
  k_scores <<<2048, 256, 0, stream>>>(enc, v, c0, scores);
  k_softmax<<<1, 1024, 0, stream>>>(scores, out + V + H);
  k_ctx    <<<256, 1024, 0, stream>>>(enc, scores, xv + H);
  k_logits2<<<(V + 3) / 4, 256, 0, stream>>>(Wout, xv, partial, bout, out);
}